// Round 1
// baseline (445.228 us; speedup 1.0000x reference)
//
#include <hip/hip_runtime.h>

// ConvMGSA on MI355X. Inputs/outputs FLOAT32; intermediates bf16.
// N=4 G=8 CIN=COUT=256 K=3 M=4 D=64 H=W=32 HW=1024.
//
// R10: attn rewrite — LDS-free K/V/q (global reads, lane-broadcast-merged),
//      shuffle-exchange of attention weights (wave == head m), rel staged
//      once per block as swizzled bf16 [3][2048] so q·rel = 3 extra dot8bf.
//      LDS 52KB -> 12KB, barriers 4 -> 1, occupancy 3 -> ~6-7 blocks/CU.
// Buffers: d_out[0:16.8M]=Q chain (q->av->hidden), d_out[16.8M:33.5M]=xb,
//          ws[0:16M]=K chain (k->y2->f), ws[16M:32M]=V chain (v->y3).

typedef unsigned short u16;
typedef unsigned int u32;
typedef __attribute__((ext_vector_type(8))) short bf16x8;
typedef __attribute__((ext_vector_type(4))) float f32x4;

__device__ __forceinline__ u32 fbits(float f) { u32 x; __builtin_memcpy(&x, &f, 4); return x; }
__device__ __forceinline__ float bf2f(u32 v) {
    u32 x = v << 16; float f; __builtin_memcpy(&f, &x, 4); return f;
}
__device__ __forceinline__ u16 f2bf(float f) {
    u32 x = fbits(f);
    u32 r = x + 0x7fffu + ((x >> 16) & 1u);
    return (u16)(r >> 16);
}
__device__ __forceinline__ u32 pack2bf(float a, float b) {
    return __builtin_amdgcn_perm(fbits(b) + 0x8000u, fbits(a) + 0x8000u, 0x07060302u);
}

__device__ __forceinline__ void unpack8(uint4 u, float* o) {
    o[0] = bf2f(u.x & 0xffff); o[1] = bf2f(u.x >> 16);
    o[2] = bf2f(u.y & 0xffff); o[3] = bf2f(u.y >> 16);
    o[4] = bf2f(u.z & 0xffff); o[5] = bf2f(u.z >> 16);
    o[6] = bf2f(u.w & 0xffff); o[7] = bf2f(u.w >> 16);
}
__device__ __forceinline__ void ld8bf(const u16* p, float* o) { unpack8(*(const uint4*)p, o); }
__device__ __forceinline__ void ld8f(const float* p, float* o) {
    float4 a = *(const float4*)p, b = *(const float4*)(p + 4);
    o[0] = a.x; o[1] = a.y; o[2] = a.z; o[3] = a.w;
    o[4] = b.x; o[5] = b.y; o[6] = b.z; o[7] = b.w;
}
__device__ __forceinline__ void st4bf(u16* p, const float* v) {
    ushort4 s; s.x = f2bf(v[0]); s.y = f2bf(v[1]); s.z = f2bf(v[2]); s.w = f2bf(v[3]);
    *(ushort4*)p = s;
}

#if defined(__has_builtin)
#if __has_builtin(__builtin_amdgcn_fdot2_f32_bf16)
#define HAVE_BFDOT 1
#endif
#endif
#ifdef HAVE_BFDOT
typedef __attribute__((ext_vector_type(2))) __bf16 v2bf;
__device__ __forceinline__ float dot2bf(u32 a, u32 b, float c) {
    return __builtin_amdgcn_fdot2_f32_bf16(__builtin_bit_cast(v2bf, a),
                                           __builtin_bit_cast(v2bf, b), c, false);
}
#else
__device__ __forceinline__ float dot2bf(u32 a, u32 b, float c) {
    return c + bf2f(a & 0xffff) * bf2f(b & 0xffff) + bf2f(a >> 16) * bf2f(b >> 16);
}
#endif
__device__ __forceinline__ float dot8bf(uint4 a, uint4 b, float c) {
    c = dot2bf(a.x, b.x, c); c = dot2bf(a.y, b.y, c);
    c = dot2bf(a.z, b.z, c); c = dot2bf(a.w, b.w, c);
    return c;
}

// ---------------- x f32 -> bf16 cast (8.39M elems) ----------------
__global__ __launch_bounds__(256) void xcast_kernel(const float* __restrict__ x,
                                                    u16* __restrict__ xb) {
    const size_t i = ((size_t)blockIdx.x * 256 + threadIdx.x) * 8;
    float4 a = *(const float4*)(x + i), b = *(const float4*)(x + i + 4);
    uint4 o;
    o.x = pack2bf(a.x, a.y); o.y = pack2bf(a.z, a.w);
    o.z = pack2bf(b.x, b.y); o.w = pack2bf(b.z, b.w);
    *(uint4*)(xb + i) = o;
}

// ================= MFMA GEMM: C[o][p] = sum_i W[g][o][i] * B[i][p] =================
// BMODE: 1=bf16 i-major (pair-pack transpose staging), 2=bf16 pixel-major
// OUTMODE: 0=bf16 pixel-major [p][g*256+o], 1=bf16 channel-major +bias(+relu)
template<int BMODE, int OUTMODE, int RELU>
__global__ __launch_bounds__(256) void gemm_kernel(
    const float* __restrict__ A, const void* __restrict__ B,
    const float* __restrict__ bias, u16* __restrict__ out) {
    __shared__ __align__(16) char smem[OUTMODE == 1 ? 64 * 132 * 4 : 20480];
    u16* Al = (u16*)smem;              // [128][40] bf16  (o, k)
    u16* Bl = (u16*)(smem + 10240);    // [128][40] bf16  (p, k)
    float* Cl = (float*)smem;          // [64][132] f32   (epilogue transpose)

    const int tid = threadIdx.x;
    const int pt = blockIdx.x, ot = blockIdx.y, ng = blockIdx.z;
    const int n = ng >> 3, g = ng & 7;
    const int p0 = pt << 7, o0 = ot << 7;
    const float* Ag = A + (size_t)g * 65536;

    const int l = tid & 63, w = tid >> 6;
    const int mq = w >> 1;
    const int mw = mq << 6, nw = (w & 1) << 6;
    const int lrow = l & 15, lk = (l >> 4) << 3;

    f32x4 acc[4][4];
    #pragma unroll
    for (int i = 0; i < 4; i++)
        #pragma unroll
        for (int j = 0; j < 4; j++) acc[i][j] = (f32x4){0.f, 0.f, 0.f, 0.f};

    for (int k0 = 0; k0 < 256; k0 += 32) {
        {   // stage A: f32 weights, rows k-contiguous, pack2bf
            const int r = tid >> 1, cb = (tid & 1) << 4;
            const float* src = Ag + (size_t)(o0 + r) * 256 + k0 + cb;
            u32* dst = (u32*)&Al[r * 40 + cb];
            #pragma unroll
            for (int q = 0; q < 4; q++) {
                float4 f = *(const float4*)(src + q * 4);
                dst[q * 2]     = pack2bf(f.x, f.y);
                dst[q * 2 + 1] = pack2bf(f.z, f.w);
            }
        }
        if (BMODE == 2) {
            const int r = tid >> 1, cb = (tid & 1) << 4;
            const u16* src = (const u16*)B + (size_t)(n * 1024 + p0 + r) * 2048 + g * 256 + k0 + cb;
            *(uint4*)&Bl[r * 40 + cb]     = *(const uint4*)src;
            *(uint4*)&Bl[r * 40 + cb + 8] = *(const uint4*)(src + 8);
        } else {
            // bf16 i-major: load rows k, k+1; v_perm pair-pack; 8 b32 writes
            const int kp = tid & 15, po = tid >> 4;
            const u16* src = (const u16*)B + (size_t)(ng * 256 + k0 + 2 * kp) * 1024 + p0 + po * 8;
            uint4 r0 = *(const uint4*)src;
            uint4 r1 = *(const uint4*)(src + 1024);
            u32 a0[4] = { r0.x, r0.y, r0.z, r0.w };
            u32 a1[4] = { r1.x, r1.y, r1.z, r1.w };
            #pragma unroll
            for (int j = 0; j < 4; j++) {
                u32 w0 = __builtin_amdgcn_perm(a1[j], a0[j], 0x05040100u);  // p=2j
                u32 w1 = __builtin_amdgcn_perm(a1[j], a0[j], 0x07060302u);  // p=2j+1
                *(u32*)&Bl[(po * 8 + 2 * j    ) * 40 + 2 * kp] = w0;
                *(u32*)&Bl[(po * 8 + 2 * j + 1) * 40 + 2 * kp] = w1;
            }
        }
        __syncthreads();
        bf16x8 af[4], bfg[4];
        #pragma unroll
        for (int i = 0; i < 4; i++) af[i]  = *(const bf16x8*)&Al[(mw + i * 16 + lrow) * 40 + lk];
        #pragma unroll
        for (int j = 0; j < 4; j++) bfg[j] = *(const bf16x8*)&Bl[(nw + j * 16 + lrow) * 40 + lk];
        #pragma unroll
        for (int i = 0; i < 4; i++)
            #pragma unroll
            for (int j = 0; j < 4; j++)
                acc[i][j] = __builtin_amdgcn_mfma_f32_16x16x32_bf16(af[i], bfg[j], acc[i][j], 0, 0, 0);
        __syncthreads();
    }

    if (OUTMODE == 0) {
        #pragma unroll
        for (int i = 0; i < 4; i++) {
            const int orow = o0 + mw + i * 16 + ((l >> 4) << 2);
            #pragma unroll
            for (int j = 0; j < 4; j++) {
                const int p = p0 + nw + j * 16 + lrow;
                float v4[4] = { acc[i][j].x, acc[i][j].y, acc[i][j].z, acc[i][j].w };
                st4bf(out + (size_t)(n * 1024 + p) * 2048 + g * 256 + orow, v4);
            }
        }
    } else {
        for (int ph = 0; ph < 2; ph++) {
            __syncthreads();
            if (mq == ph) {
                #pragma unroll
                for (int i = 0; i < 4; i++) {
                    const int rl = i * 16 + ((l >> 4) << 2);
                    #pragma unroll
                    for (int j = 0; j < 4; j++) {
                        const int c = nw + j * 16 + lrow;
                        Cl[(rl    ) * 132 + c] = acc[i][j].x;
                        Cl[(rl + 1) * 132 + c] = acc[i][j].y;
                        Cl[(rl + 2) * 132 + c] = acc[i][j].z;
                        Cl[(rl + 3) * 132 + c] = acc[i][j].w;
                    }
                }
            }
            __syncthreads();
            {
                const int row = tid >> 2, pc = (tid & 3) << 5;
                const int og = o0 + ph * 64 + row;
                const float bb = bias ? bias[g * 256 + og] : 0.f;
                u32 pk[16];
                #pragma unroll
                for (int q = 0; q < 8; q++) {
                    float4 f = *(const float4*)&Cl[row * 132 + pc + q * 4];
                    float a0 = f.x + bb, a1 = f.y + bb, a2 = f.z + bb, a3 = f.w + bb;
                    if (RELU) {
                        a0 = fmaxf(a0, 0.f); a1 = fmaxf(a1, 0.f);
                        a2 = fmaxf(a2, 0.f); a3 = fmaxf(a3, 0.f);
                    }
                    pk[q * 2]     = pack2bf(a0, a1);
                    pk[q * 2 + 1] = pack2bf(a2, a3);
                }
                u16* dst = out + (size_t)(ng * 256 + og) * 1024 + p0 + pc;
                #pragma unroll
                for (int q = 0; q < 4; q++) *(uint4*)(dst + q * 8) = *(uint4*)&pk[q * 4];
            }
        }
    }
}

// ---------------- attention v2: LDS-free K/V/q, shuffle exchange ----------------
// Wave w == head m (lanes l = g*8+e in QK, l = g*8+d0idx in AV; all exchange
// is wave-local). Only LDS: relS[3][2048] bf16, XOR-swizzled, so the q·rel
// term is 3 extra dot8bf per c8 (pseudo-neighbors 9..11).
__device__ __forceinline__ int swzb(int off) { return off ^ (((off >> 9) & 7) << 4); }

__global__ __launch_bounds__(256, 6) void attn_kernel(
    const u16* __restrict__ qt, const u16* __restrict__ kt,
    const u16* __restrict__ vt, const float* __restrict__ hm,
    const float* __restrict__ wm, u16* __restrict__ av) {
    __shared__ __align__(16) u16 relS[3 * 2048];
    const int tid = threadIdx.x;
    const int bx = blockIdx.x, n = blockIdx.y;
    const int p = ((bx & 7) << 7) | (bx >> 3);   // XCD-contiguous pixel ranges
    const int ph = p >> 5, pw = p & 31;
    const size_t nimg = (size_t)n * 1024;

    // ---- stage rel: relS[idx][c] bf16 (transpose of [c][3] f32), swizzled ----
    {
        const int c0 = tid << 3;
        const float* rb = (tid < 128) ? (hm + (size_t)c0 * 3)
                                      : (wm + (size_t)(c0 - 1024) * 3);
        float r[24];
        #pragma unroll
        for (int q = 0; q < 6; q++) {
            float4 f = *(const float4*)(rb + q * 4);
            r[q * 4] = f.x; r[q * 4 + 1] = f.y; r[q * 4 + 2] = f.z; r[q * 4 + 3] = f.w;
        }
        #pragma unroll
        for (int idx = 0; idx < 3; idx++) {
            u32 pk[4];
            #pragma unroll
            for (int j = 0; j < 4; j++)
                pk[j] = pack2bf(r[(2 * j) * 3 + idx], r[(2 * j + 1) * 3 + idx]);
            *(uint4*)((char*)relS + swzb(idx * 4096 + c0 * 2)) = *(uint4*)pk;
        }
    }

    int npix[9]; unsigned inb = 0;
    #pragma unroll
    for (int ij = 0; ij < 9; ij++) {
        int hs = ph + ij / 3 - 1, wcol = pw + ij % 3 - 1;
        npix[ij] = hs * 32 + wcol;
        if (((unsigned)hs < 32u) && ((unsigned)wcol < 32u)) inb |= (1u << ij);
    }

    const int l = tid & 63;
    const int e_th = tid & 7, g_th = (tid >> 3) & 7, m_th = tid >> 6;
    const int ck = e_th * 256 + m_th * 64;                 // k / rel channel base
    const u16* qp = qt + (nimg + p) * 2048 + g_th * 256 + m_th * 64;

    __syncthreads();

    // ---- QK: 12 uniform bf16 dots per c8 (9 neighbors + 3 rel pseudo-cols) ----
    float sc[12] = {};
    for (int c8 = 0; c8 < 8; c8++) {
        const uint4 qv = *(const uint4*)(qp + c8 * 8);
        #pragma unroll
        for (int idx = 0; idx < 3; idx++) {
            uint4 rv = *(const uint4*)((const char*)relS +
                                       swzb(idx * 4096 + (ck + c8 * 8) * 2));
            sc[9 + idx] = dot8bf(qv, rv, sc[9 + idx]);
        }
        #pragma unroll
        for (int ij = 0; ij < 9; ij++) {
            if (inb & (1u << ij)) {
                uint4 kv = *(const uint4*)(kt + (nimg + npix[ij]) * 2048 + ck + c8 * 8);
                sc[ij] = dot8bf(qv, kv, sc[ij]);
            }
        }
    }
    // OOB neighbors keep sc=0 (zero-padded K) but still get the rel term,
    // and participate in softmax — matches reference unfold+rel semantics.
    #pragma unroll
    for (int ij = 0; ij < 9; ij++)
        sc[ij] += sc[9 + ((e_th < 4) ? (ij / 3) : (ij % 3))];

    float mx = sc[0];
    #pragma unroll
    for (int ij = 1; ij < 9; ij++) mx = fmaxf(mx, sc[ij]);
    mx = fmaxf(mx, __shfl_xor(mx, 1));
    mx = fmaxf(mx, __shfl_xor(mx, 2));
    mx = fmaxf(mx, __shfl_xor(mx, 4));
    float sum = 0.f;
    #pragma unroll
    for (int ij = 0; ij < 9; ij++) { sc[ij] = __expf(sc[ij] - mx); sum += sc[ij]; }
    sum += __shfl_xor(sum, 1); sum += __shfl_xor(sum, 2); sum += __shfl_xor(sum, 4);
    const float rinv = 1.f / sum;
    #pragma unroll
    for (int ij = 0; ij < 9; ij++) sc[ij] *= rinv;

    // ---- AV: lane (g', d0) pulls attn[(m,g'),e,ij] from lane g'*8+e via shfl ----
    const int d0 = (l & 7) << 3;
    const int srcb = l & 0x38;                             // g'<<3
    float acc[8] = {};
    for (int ij = 0; ij < 9; ij++) {
        if (!(inb & (1u << ij))) continue;
        const u16* vp = vt + (nimg + npix[ij]) * 2048 + m_th * 64 + d0;
        #pragma unroll
        for (int e = 0; e < 8; e++) {
            const float a = __shfl(sc[ij], srcb | e);
            uint4 vv = *(const uint4*)(vp + e * 256);
            float v8[8];
            unpack8(vv, v8);
            #pragma unroll
            for (int u = 0; u < 8; u++) acc[u] += a * v8[u];
        }
    }
    const int c0 = (l >> 3) * 256 + m_th * 64 + d0;
    st4bf(av + (nimg + p) * 2048 + c0, acc);
    st4bf(av + (nimg + p) * 2048 + c0 + 4, acc + 4);
}

// ---------------- LN over d=64 of A+B; scramble-contiguous write ----------------
__global__ __launch_bounds__(256) void ln_kernel(
    const void* __restrict__ A, int aF32, const void* __restrict__ B, int bF32,
    const float* __restrict__ gamma, const float* __restrict__ beta,
    void* __restrict__ out, int outF32) {
    __shared__ float s[64][68];
    __shared__ float red[2][4][64];
    __shared__ float mu_s[64], rs_s[64], gam[64], bet[64];
    const int tid = threadIdx.x;
    const int pt = blockIdx.x, m = blockIdx.y, ng = blockIdx.z;
    const int n = ng >> 3, g = ng & 7;
    const int p0 = pt << 6;
    if (tid < 64) { gam[tid] = gamma[tid]; bet[tid] = beta[tid]; }

    const int sd = tid >> 2, sp = (tid & 3) << 4;
    {
        const size_t base = (size_t)((n * 8 + g) * 256 + m * 64 + sd) * 1024 + p0 + sp;
        #pragma unroll
        for (int half = 0; half < 2; half++) {
            float a8[8], b8[8];
            if (aF32) ld8f((const float*)A + base + half * 8, a8);
            else      ld8bf((const u16*)A + base + half * 8, a8);
            if (bF32) ld8f((const float*)B + base + half * 8, b8);
            else      ld8bf((const u16*)B + base + half * 8, b8);
            #pragma unroll
            for (int u = 0; u < 8; u++) s[sd][sp + half * 8 + u] = a8[u] + b8[u];
        }
    }
    __syncthreads();
    const int rp = tid & 63, rq = tid >> 6;
    float sm = 0.f, sq = 0.f;
    #pragma unroll
    for (int u = 0; u < 16; u++) { float v = s[rq * 16 + u][rp]; sm += v; sq += v * v; }
    red[0][rq][rp] = sm; red[1][rq][rp] = sq;
    __syncthreads();
    if (tid < 64) {
        float s2 = red[0][0][tid] + red[0][1][tid] + red[0][2][tid] + red[0][3][tid];
        float q2 = red[1][0][tid] + red[1][1][tid] + red[1][2][tid] + red[1][3][tid];
        float mu = s2 * (1.f / 64.f);
        float var = q2 * (1.f / 64.f) - mu * mu;
        mu_s[tid] = mu; rs_s[tid] = rsqrtf(var + 1e-5f);
    }
    __syncthreads();
    const int op = tid >> 2, od = (tid & 3) << 4;
    const float mu = mu_s[op], rs = rs_s[op];
    const size_t obase = (size_t)n * 2097152 + (size_t)(p0 + op) * 2048 + m * 512 + g * 64 + od;
    #pragma unroll
    for (int q4 = 0; q4 < 4; q4++) {
        float v4[4];
        #pragma unroll
        for (int u = 0; u < 4; u++) {
            int d = od + q4 * 4 + u;
            v4[u] = (s[d][op] - mu) * rs * gam[d] + bet[d];
        }
        if (outF32) {
            float4 f4; f4.x = v4[0]; f4.y = v4[1]; f4.z = v4[2]; f4.w = v4[3];
            *(float4*)((float*)out + obase + q4 * 4) = f4;
        } else {
            st4bf((u16*)out + obase + q4 * 4, v4);
        }
    }
}

extern "C" void kernel_launch(void* const* d_in, const int* in_sizes, int n_in,
                              void* d_out, int out_size, void* d_ws, size_t ws_size,
                              hipStream_t stream) {
    const float* x   = (const float*)d_in[0];
    const float* wq  = (const float*)d_in[1];
    const float* wk  = (const float*)d_in[2];
    const float* wv  = (const float*)d_in[3];
    const float* hm  = (const float*)d_in[4];
    const float* wm  = (const float*)d_in[5];
    const float* wc  = (const float*)d_in[6];
    const float* bc  = (const float*)d_in[7];
    const float* wf1 = (const float*)d_in[8];
    const float* bf1 = (const float*)d_in[9];
    const float* wf2 = (const float*)d_in[10];
    const float* bf2w = (const float*)d_in[11];
    const float* g1  = (const float*)d_in[12];
    const float* b1  = (const float*)d_in[13];
    const float* g2  = (const float*)d_in[14];
    const float* b2  = (const float*)d_in[15];
    char* ws = (char*)d_ws;
    u16* bufQ = (u16*)d_out;                     // d_out lower half: q -> av -> hidden
    u16* xb   = bufQ + 8388608;                  // d_out upper half: bf16 x (dead before LN2)
    u16* bufK = (u16*)(ws);                      // k -> y2 -> f
    u16* bufV = (u16*)(ws + 16777216);           // v -> y3

    const dim3 gg(8, 2, 32), gb(256);
    xcast_kernel<<<dim3(4096), gb, 0, stream>>>(x, xb);
    gemm_kernel<1, 0, 0><<<gg, gb, 0, stream>>>(wq, xb, nullptr, bufQ);
    gemm_kernel<1, 0, 0><<<gg, gb, 0, stream>>>(wk, xb, nullptr, bufK);
    gemm_kernel<1, 0, 0><<<gg, gb, 0, stream>>>(wv, xb, nullptr, bufV);
    attn_kernel<<<dim3(1024, 4), gb, 0, stream>>>(bufQ, bufK, bufV, hm, wm, bufQ);
    gemm_kernel<2, 1, 0><<<gg, gb, 0, stream>>>(wc, bufQ, bc, bufK);
    ln_kernel<<<dim3(16, 4, 32), gb, 0, stream>>>(xb, 0, bufK, 0, g1, b1, bufV, 0);
    gemm_kernel<1, 1, 1><<<gg, gb, 0, stream>>>(wf1, bufV, bf1, bufQ);
    gemm_kernel<1, 1, 0><<<gg, gb, 0, stream>>>(wf2, bufQ, bf2w, bufK);
    ln_kernel<<<dim3(16, 4, 32), gb, 0, stream>>>(bufV, 0, bufK, 0, g2, b2, d_out, 1);
}

// Round 2
// 337.021 us; speedup vs baseline: 1.3211x; 1.3211x over previous
//
#include <hip/hip_runtime.h>

// ConvMGSA on MI355X. Inputs/outputs FLOAT32; intermediates bf16.
// N=4 G=8 CIN=COUT=256 K=3 M=4 D=64 H=W=32 HW=1024.
//
// R11: attn v3 — back to LDS staging (R10 post-mortem: scattered L2 gathers
//      lost to staged reads), but 36.9KB XOR-swizzled kvb [ij][m][e][d]
//      (no pads) -> 4 blocks/CU; relS overlaid in kvb for a qrel pre-phase
//      (kills R9's 48 f32x4 loads + ~190 FMA/thread); q in regs; attn
//      exchanged via wave-local shfl (wave == m). QKV GEMMs fused (z=96).
// Buffers: d_out[0:16.8M]=Q chain (q->av->hidden), d_out[16.8M:33.5M]=xb,
//          ws[0:16M]=K chain (k->y2->f), ws[16M:32M]=V chain (v->y3).

typedef unsigned short u16;
typedef unsigned int u32;
typedef __attribute__((ext_vector_type(8))) short bf16x8;
typedef __attribute__((ext_vector_type(4))) float f32x4;

__device__ __forceinline__ u32 fbits(float f) { u32 x; __builtin_memcpy(&x, &f, 4); return x; }
__device__ __forceinline__ float bf2f(u32 v) {
    u32 x = v << 16; float f; __builtin_memcpy(&f, &x, 4); return f;
}
__device__ __forceinline__ u16 f2bf(float f) {
    u32 x = fbits(f);
    u32 r = x + 0x7fffu + ((x >> 16) & 1u);
    return (u16)(r >> 16);
}
__device__ __forceinline__ u32 pack2bf(float a, float b) {
    return __builtin_amdgcn_perm(fbits(b) + 0x8000u, fbits(a) + 0x8000u, 0x07060302u);
}

__device__ __forceinline__ void unpack8(uint4 u, float* o) {
    o[0] = bf2f(u.x & 0xffff); o[1] = bf2f(u.x >> 16);
    o[2] = bf2f(u.y & 0xffff); o[3] = bf2f(u.y >> 16);
    o[4] = bf2f(u.z & 0xffff); o[5] = bf2f(u.z >> 16);
    o[6] = bf2f(u.w & 0xffff); o[7] = bf2f(u.w >> 16);
}
__device__ __forceinline__ void ld8bf(const u16* p, float* o) { unpack8(*(const uint4*)p, o); }
__device__ __forceinline__ void ld8f(const float* p, float* o) {
    float4 a = *(const float4*)p, b = *(const float4*)(p + 4);
    o[0] = a.x; o[1] = a.y; o[2] = a.z; o[3] = a.w;
    o[4] = b.x; o[5] = b.y; o[6] = b.z; o[7] = b.w;
}
__device__ __forceinline__ void st4bf(u16* p, const float* v) {
    ushort4 s; s.x = f2bf(v[0]); s.y = f2bf(v[1]); s.z = f2bf(v[2]); s.w = f2bf(v[3]);
    *(ushort4*)p = s;
}

#if defined(__has_builtin)
#if __has_builtin(__builtin_amdgcn_fdot2_f32_bf16)
#define HAVE_BFDOT 1
#endif
#endif
#ifdef HAVE_BFDOT
typedef __attribute__((ext_vector_type(2))) __bf16 v2bf;
__device__ __forceinline__ float dot2bf(u32 a, u32 b, float c) {
    return __builtin_amdgcn_fdot2_f32_bf16(__builtin_bit_cast(v2bf, a),
                                           __builtin_bit_cast(v2bf, b), c, false);
}
#else
__device__ __forceinline__ float dot2bf(u32 a, u32 b, float c) {
    return c + bf2f(a & 0xffff) * bf2f(b & 0xffff) + bf2f(a >> 16) * bf2f(b >> 16);
}
#endif
__device__ __forceinline__ float dot8bf(uint4 a, uint4 b, float c) {
    c = dot2bf(a.x, b.x, c); c = dot2bf(a.y, b.y, c);
    c = dot2bf(a.z, b.z, c); c = dot2bf(a.w, b.w, c);
    return c;
}

// ---------------- x f32 -> bf16 cast (8.39M elems) ----------------
__global__ __launch_bounds__(256) void xcast_kernel(const float* __restrict__ x,
                                                    u16* __restrict__ xb) {
    const size_t i = ((size_t)blockIdx.x * 256 + threadIdx.x) * 8;
    float4 a = *(const float4*)(x + i), b = *(const float4*)(x + i + 4);
    uint4 o;
    o.x = pack2bf(a.x, a.y); o.y = pack2bf(a.z, a.w);
    o.z = pack2bf(b.x, b.y); o.w = pack2bf(b.z, b.w);
    *(uint4*)(xb + i) = o;
}

// ================= MFMA GEMM: C[o][p] = sum_i W[g][o][i] * B[i][p] =================
// BMODE: 1=bf16 i-major (pair-pack transpose staging), 2=bf16 pixel-major
// OUTMODE: 0=bf16 pixel-major [p][g*256+o], 1=bf16 channel-major +bias(+relu)
// Fused multi-op: z >= 32 selects (A,out) pair 1 or 2 (QKV in one dispatch).
template<int BMODE, int OUTMODE, int RELU>
__global__ __launch_bounds__(256) void gemm_kernel(
    const float* __restrict__ A0, const float* __restrict__ A1,
    const float* __restrict__ A2, const void* __restrict__ B,
    const float* __restrict__ bias,
    u16* __restrict__ O0, u16* __restrict__ O1, u16* __restrict__ O2) {
    __shared__ __align__(16) char smem[OUTMODE == 1 ? 64 * 132 * 4 : 20480];
    u16* Al = (u16*)smem;              // [128][40] bf16  (o, k)
    u16* Bl = (u16*)(smem + 10240);    // [128][40] bf16  (p, k)
    float* Cl = (float*)smem;          // [64][132] f32   (epilogue transpose)

    const int tid = threadIdx.x;
    const int pt = blockIdx.x, ot = blockIdx.y;
    const int ngz = blockIdx.z, sel = ngz >> 5, ng = ngz & 31;
    const float* A = (sel == 0) ? A0 : (sel == 1) ? A1 : A2;
    u16* out      = (sel == 0) ? O0 : (sel == 1) ? O1 : O2;
    const int n = ng >> 3, g = ng & 7;
    const int p0 = pt << 7, o0 = ot << 7;
    const float* Ag = A + (size_t)g * 65536;

    const int l = tid & 63, w = tid >> 6;
    const int mq = w >> 1;
    const int mw = mq << 6, nw = (w & 1) << 6;
    const int lrow = l & 15, lk = (l >> 4) << 3;

    f32x4 acc[4][4];
    #pragma unroll
    for (int i = 0; i < 4; i++)
        #pragma unroll
        for (int j = 0; j < 4; j++) acc[i][j] = (f32x4){0.f, 0.f, 0.f, 0.f};

    for (int k0 = 0; k0 < 256; k0 += 32) {
        {   // stage A: f32 weights, rows k-contiguous, pack2bf
            const int r = tid >> 1, cb = (tid & 1) << 4;
            const float* src = Ag + (size_t)(o0 + r) * 256 + k0 + cb;
            u32* dst = (u32*)&Al[r * 40 + cb];
            #pragma unroll
            for (int q = 0; q < 4; q++) {
                float4 f = *(const float4*)(src + q * 4);
                dst[q * 2]     = pack2bf(f.x, f.y);
                dst[q * 2 + 1] = pack2bf(f.z, f.w);
            }
        }
        if (BMODE == 2) {
            const int r = tid >> 1, cb = (tid & 1) << 4;
            const u16* src = (const u16*)B + (size_t)(n * 1024 + p0 + r) * 2048 + g * 256 + k0 + cb;
            *(uint4*)&Bl[r * 40 + cb]     = *(const uint4*)src;
            *(uint4*)&Bl[r * 40 + cb + 8] = *(const uint4*)(src + 8);
        } else {
            // bf16 i-major: load rows k, k+1; v_perm pair-pack; 8 b32 writes
            const int kp = tid & 15, po = tid >> 4;
            const u16* src = (const u16*)B + (size_t)(ng * 256 + k0 + 2 * kp) * 1024 + p0 + po * 8;
            uint4 r0 = *(const uint4*)src;
            uint4 r1 = *(const uint4*)(src + 1024);
            u32 a0[4] = { r0.x, r0.y, r0.z, r0.w };
            u32 a1[4] = { r1.x, r1.y, r1.z, r1.w };
            #pragma unroll
            for (int j = 0; j < 4; j++) {
                u32 w0 = __builtin_amdgcn_perm(a1[j], a0[j], 0x05040100u);  // p=2j
                u32 w1 = __builtin_amdgcn_perm(a1[j], a0[j], 0x07060302u);  // p=2j+1
                *(u32*)&Bl[(po * 8 + 2 * j    ) * 40 + 2 * kp] = w0;
                *(u32*)&Bl[(po * 8 + 2 * j + 1) * 40 + 2 * kp] = w1;
            }
        }
        __syncthreads();
        bf16x8 af[4], bfg[4];
        #pragma unroll
        for (int i = 0; i < 4; i++) af[i]  = *(const bf16x8*)&Al[(mw + i * 16 + lrow) * 40 + lk];
        #pragma unroll
        for (int j = 0; j < 4; j++) bfg[j] = *(const bf16x8*)&Bl[(nw + j * 16 + lrow) * 40 + lk];
        #pragma unroll
        for (int i = 0; i < 4; i++)
            #pragma unroll
            for (int j = 0; j < 4; j++)
                acc[i][j] = __builtin_amdgcn_mfma_f32_16x16x32_bf16(af[i], bfg[j], acc[i][j], 0, 0, 0);
        __syncthreads();
    }

    if (OUTMODE == 0) {
        #pragma unroll
        for (int i = 0; i < 4; i++) {
            const int orow = o0 + mw + i * 16 + ((l >> 4) << 2);
            #pragma unroll
            for (int j = 0; j < 4; j++) {
                const int p = p0 + nw + j * 16 + lrow;
                float v4[4] = { acc[i][j].x, acc[i][j].y, acc[i][j].z, acc[i][j].w };
                st4bf(out + (size_t)(n * 1024 + p) * 2048 + g * 256 + orow, v4);
            }
        }
    } else {
        for (int ph = 0; ph < 2; ph++) {
            __syncthreads();
            if (mq == ph) {
                #pragma unroll
                for (int i = 0; i < 4; i++) {
                    const int rl = i * 16 + ((l >> 4) << 2);
                    #pragma unroll
                    for (int j = 0; j < 4; j++) {
                        const int c = nw + j * 16 + lrow;
                        Cl[(rl    ) * 132 + c] = acc[i][j].x;
                        Cl[(rl + 1) * 132 + c] = acc[i][j].y;
                        Cl[(rl + 2) * 132 + c] = acc[i][j].z;
                        Cl[(rl + 3) * 132 + c] = acc[i][j].w;
                    }
                }
            }
            __syncthreads();
            {
                const int row = tid >> 2, pc = (tid & 3) << 5;
                const int og = o0 + ph * 64 + row;
                const float bb = bias ? bias[g * 256 + og] : 0.f;
                u32 pk[16];
                #pragma unroll
                for (int q = 0; q < 8; q++) {
                    float4 f = *(const float4*)&Cl[row * 132 + pc + q * 4];
                    float a0 = f.x + bb, a1 = f.y + bb, a2 = f.z + bb, a3 = f.w + bb;
                    if (RELU) {
                        a0 = fmaxf(a0, 0.f); a1 = fmaxf(a1, 0.f);
                        a2 = fmaxf(a2, 0.f); a3 = fmaxf(a3, 0.f);
                    }
                    pk[q * 2]     = pack2bf(a0, a1);
                    pk[q * 2 + 1] = pack2bf(a2, a3);
                }
                u16* dst = out + (size_t)(ng * 256 + og) * 1024 + p0 + pc;
                #pragma unroll
                for (int q = 0; q < 4; q++) *(uint4*)(dst + q * 8) = *(uint4*)&pk[q * 4];
            }
        }
    }
}

// ---------------- attention v3: 36.9KB swizzled LDS, 4 blocks/CU ----------------
// kvb tile layout (4KB/tile, no pads): byte = ij*4096 + m*1024 + e*128 +
//   ((dblk^e)&7)*16  -> banks 4*(dblk^e): conflict-free stage/QK/AV.
// relS (bf16 [3][2048], swzb-swizzled) overlaid in kvb[0:12KB) for the qrel
// pre-phase, then overwritten by K. q in regs; attn via wave-local shfl.
__device__ __forceinline__ int swzb(int off) { return off ^ (((off >> 9) & 7) << 4); }

__global__ __launch_bounds__(256, 4) void attn_kernel(
    const u16* __restrict__ qt, const u16* __restrict__ kt,
    const u16* __restrict__ vt, const float* __restrict__ hm,
    const float* __restrict__ wm, u16* __restrict__ av) {
    __shared__ __align__(16) char kvb[9 * 4096];
    const int tid = threadIdx.x;
    const int bx = blockIdx.x, n = blockIdx.y;
    const int p = ((bx & 7) << 7) | (bx >> 3);   // XCD-contiguous pixel ranges
    const int ph = p >> 5, pw = p & 31;
    const size_t nimg = (size_t)n * 1024;

    int npix[9]; unsigned inb = 0;
    #pragma unroll
    for (int ij = 0; ij < 9; ij++) {
        int hs = ph + ij / 3 - 1, wc = pw + ij % 3 - 1;
        npix[ij] = hs * 32 + wc;
        if (((unsigned)hs < 32u) && ((unsigned)wc < 32u)) inb |= (1u << ij);
    }

    const int e_th = tid & 7, g_th = (tid >> 3) & 7, m_th = tid >> 6;

    // ---- q into regs (broadcast-merged across the 8 e-lanes) ----
    uint4 qv[8];
    {
        const u16* qp = qt + (nimg + p) * 2048 + g_th * 256 + m_th * 64;
        #pragma unroll
        for (int c8 = 0; c8 < 8; c8++) qv[c8] = *(const uint4*)(qp + c8 * 8);
    }

    // ---- Phase A: stage relS = bf16 transpose of hm/wm into kvb[0:12KB) ----
    {
        const int c0 = tid << 3;
        const float* rb = (tid < 128) ? (hm + (size_t)c0 * 3)
                                      : (wm + (size_t)(c0 - 1024) * 3);
        float r[24];
        #pragma unroll
        for (int q = 0; q < 6; q++) {
            float4 f = *(const float4*)(rb + q * 4);
            r[q * 4] = f.x; r[q * 4 + 1] = f.y; r[q * 4 + 2] = f.z; r[q * 4 + 3] = f.w;
        }
        #pragma unroll
        for (int idx = 0; idx < 3; idx++) {
            u32 pk[4];
            #pragma unroll
            for (int j = 0; j < 4; j++)
                pk[j] = pack2bf(r[(2 * j) * 3 + idx], r[(2 * j + 1) * 3 + idx]);
            *(uint4*)(kvb + swzb(idx * 4096 + c0 * 2)) = *(uint4*)pk;
        }
    }
    __syncthreads();

    // ---- Phase B: qrel[idx] = q · relS[idx] over this thread's rel slice ----
    float qrel3[3] = {};
    {
        const int ckr = e_th * 256 + m_th * 64;
        #pragma unroll
        for (int c8 = 0; c8 < 8; c8++) {
            #pragma unroll
            for (int idx = 0; idx < 3; idx++) {
                uint4 rv = *(const uint4*)(kvb + swzb(idx * 4096 + (ckr + c8 * 8) * 2));
                qrel3[idx] = dot8bf(qv[c8], rv, qrel3[idx]);
            }
        }
    }
    __syncthreads();   // relS dead, kvb free for K

    // ---- Phase C: stage K (swizzled) ----
    const int stoff = ((tid >> 3) & 3) * 1024 + (tid >> 5) * 128
                    + ((((tid & 7) ^ (tid >> 5)) & 7) << 4);
    const int c_s = tid << 3;
    #pragma unroll
    for (int ij = 0; ij < 9; ij++)
        if (inb & (1u << ij))
            *(uint4*)(kvb + ij * 4096 + stoff) =
                *(const uint4*)(kt + (nimg + npix[ij]) * 2048 + c_s);
    __syncthreads();

    // ---- Phase D: QK + softmax ----
    float sc[9] = {};
    const int qkb = m_th * 1024 + e_th * 128;
    #pragma unroll
    for (int c8 = 0; c8 < 8; c8++) {
        const int sw = ((c8 ^ e_th) & 7) << 4;
        #pragma unroll
        for (int ij = 0; ij < 9; ij++)
            if (inb & (1u << ij)) {
                uint4 kv = *(const uint4*)(kvb + ij * 4096 + qkb + sw);
                sc[ij] = dot8bf(qv[c8], kv, sc[ij]);
            }
    }
    // OOB neighbors keep sc=0 (zero-padded K) but still get the rel term,
    // and participate in softmax — matches reference unfold+rel semantics.
    #pragma unroll
    for (int ij = 0; ij < 9; ij++)
        sc[ij] += qrel3[(e_th < 4) ? (ij / 3) : (ij % 3)];

    float mx = sc[0];
    #pragma unroll
    for (int ij = 1; ij < 9; ij++) mx = fmaxf(mx, sc[ij]);
    mx = fmaxf(mx, __shfl_xor(mx, 1));
    mx = fmaxf(mx, __shfl_xor(mx, 2));
    mx = fmaxf(mx, __shfl_xor(mx, 4));
    float sum = 0.f;
    #pragma unroll
    for (int ij = 0; ij < 9; ij++) { sc[ij] = __expf(sc[ij] - mx); sum += sc[ij]; }
    sum += __shfl_xor(sum, 1); sum += __shfl_xor(sum, 2); sum += __shfl_xor(sum, 4);
    const float rinv = 1.f / sum;
    #pragma unroll
    for (int ij = 0; ij < 9; ij++) sc[ij] *= rinv;

    __syncthreads();   // all K reads done

    // ---- Phase E: stage V (overwrites kvb) ----
    #pragma unroll
    for (int ij = 0; ij < 9; ij++)
        if (inb & (1u << ij))
            *(uint4*)(kvb + ij * 4096 + stoff) =
                *(const uint4*)(vt + (nimg + npix[ij]) * 2048 + c_s);
    __syncthreads();

    // ---- Phase F: AV — lane (g', d0) pulls attn[(m,g'),e,ij] via shfl ----
    const int l = tid & 63;
    const int db = l & 7, srcb = l & 0x38;
    const int avb = m_th * 1024;
    float acc[8] = {};
    #pragma unroll
    for (int ij = 0; ij < 9; ij++) {
        if (!(inb & (1u << ij))) continue;
        #pragma unroll
        for (int e = 0; e < 8; e++) {
            const float a = __shfl(sc[ij], srcb | e);
            uint4 vv = *(const uint4*)(kvb + ij * 4096 + avb + e * 128 + (((db ^ e) & 7) << 4));
            float v8[8];
            unpack8(vv, v8);
            #pragma unroll
            for (int u = 0; u < 8; u++) acc[u] += a * v8[u];
        }
    }
    const int c0 = (l >> 3) * 256 + m_th * 64 + (db << 3);
    st4bf(av + (nimg + p) * 2048 + c0, acc);
    st4bf(av + (nimg + p) * 2048 + c0 + 4, acc + 4);
}

// ---------------- LN over d=64 of A+B; scramble-contiguous write ----------------
__global__ __launch_bounds__(256) void ln_kernel(
    const void* __restrict__ A, int aF32, const void* __restrict__ B, int bF32,
    const float* __restrict__ gamma, const float* __restrict__ beta,
    void* __restrict__ out, int outF32) {
    __shared__ float s[64][68];
    __shared__ float red[2][4][64];
    __shared__ float mu_s[64], rs_s[64], gam[64], bet[64];
    const int tid = threadIdx.x;
    const int pt = blockIdx.x, m = blockIdx.y, ng = blockIdx.z;
    const int n = ng >> 3, g = ng & 7;
    const int p0 = pt << 6;
    if (tid < 64) { gam[tid] = gamma[tid]; bet[tid] = beta[tid]; }

    const int sd = tid >> 2, sp = (tid & 3) << 4;
    {
        const size_t base = (size_t)((n * 8 + g) * 256 + m * 64 + sd) * 1024 + p0 + sp;
        #pragma unroll
        for (int half = 0; half < 2; half++) {
            float a8[8], b8[8];
            if (aF32) ld8f((const float*)A + base + half * 8, a8);
            else      ld8bf((const u16*)A + base + half * 8, a8);
            if (bF32) ld8f((const float*)B + base + half * 8, b8);
            else      ld8bf((const u16*)B + base + half * 8, b8);
            #pragma unroll
            for (int u = 0; u < 8; u++) s[sd][sp + half * 8 + u] = a8[u] + b8[u];
        }
    }
    __syncthreads();
    const int rp = tid & 63, rq = tid >> 6;
    float sm = 0.f, sq = 0.f;
    #pragma unroll
    for (int u = 0; u < 16; u++) { float v = s[rq * 16 + u][rp]; sm += v; sq += v * v; }
    red[0][rq][rp] = sm; red[1][rq][rp] = sq;
    __syncthreads();
    if (tid < 64) {
        float s2 = red[0][0][tid] + red[0][1][tid] + red[0][2][tid] + red[0][3][tid];
        float q2 = red[1][0][tid] + red[1][1][tid] + red[1][2][tid] + red[1][3][tid];
        float mu = s2 * (1.f / 64.f);
        float var = q2 * (1.f / 64.f) - mu * mu;
        mu_s[tid] = mu; rs_s[tid] = rsqrtf(var + 1e-5f);
    }
    __syncthreads();
    const int op = tid >> 2, od = (tid & 3) << 4;
    const float mu = mu_s[op], rs = rs_s[op];
    const size_t obase = (size_t)n * 2097152 + (size_t)(p0 + op) * 2048 + m * 512 + g * 64 + od;
    #pragma unroll
    for (int q4 = 0; q4 < 4; q4++) {
        float v4[4];
        #pragma unroll
        for (int u = 0; u < 4; u++) {
            int d = od + q4 * 4 + u;
            v4[u] = (s[d][op] - mu) * rs * gam[d] + bet[d];
        }
        if (outF32) {
            float4 f4; f4.x = v4[0]; f4.y = v4[1]; f4.z = v4[2]; f4.w = v4[3];
            *(float4*)((float*)out + obase + q4 * 4) = f4;
        } else {
            st4bf((u16*)out + obase + q4 * 4, v4);
        }
    }
}

extern "C" void kernel_launch(void* const* d_in, const int* in_sizes, int n_in,
                              void* d_out, int out_size, void* d_ws, size_t ws_size,
                              hipStream_t stream) {
    const float* x   = (const float*)d_in[0];
    const float* wq  = (const float*)d_in[1];
    const float* wk  = (const float*)d_in[2];
    const float* wv  = (const float*)d_in[3];
    const float* hm  = (const float*)d_in[4];
    const float* wm  = (const float*)d_in[5];
    const float* wc  = (const float*)d_in[6];
    const float* bc  = (const float*)d_in[7];
    const float* wf1 = (const float*)d_in[8];
    const float* bf1 = (const float*)d_in[9];
    const float* wf2 = (const float*)d_in[10];
    const float* bf2w = (const float*)d_in[11];
    const float* g1  = (const float*)d_in[12];
    const float* b1  = (const float*)d_in[13];
    const float* g2  = (const float*)d_in[14];
    const float* b2  = (const float*)d_in[15];
    char* ws = (char*)d_ws;
    u16* bufQ = (u16*)d_out;                     // d_out lower half: q -> av -> hidden
    u16* xb   = bufQ + 8388608;                  // d_out upper half: bf16 x (dead before LN2)
    u16* bufK = (u16*)(ws);                      // k -> y2 -> f
    u16* bufV = (u16*)(ws + 16777216);           // v -> y3

    const dim3 gg(8, 2, 32), gq(8, 2, 96), gb(256);
    xcast_kernel<<<dim3(4096), gb, 0, stream>>>(x, xb);
    gemm_kernel<1, 0, 0><<<gq, gb, 0, stream>>>(wq, wk, wv, xb, nullptr, bufQ, bufK, bufV);
    attn_kernel<<<dim3(1024, 4), gb, 0, stream>>>(bufQ, bufK, bufV, hm, wm, bufQ);
    gemm_kernel<2, 1, 0><<<gg, gb, 0, stream>>>(wc, wc, wc, bufQ, bc, bufK, bufK, bufK);
    ln_kernel<<<dim3(16, 4, 32), gb, 0, stream>>>(xb, 0, bufK, 0, g1, b1, bufV, 0);
    gemm_kernel<1, 1, 1><<<gg, gb, 0, stream>>>(wf1, wf1, wf1, bufV, bf1, bufQ, bufQ, bufQ);
    gemm_kernel<1, 1, 0><<<gg, gb, 0, stream>>>(wf2, wf2, wf2, bufQ, bf2w, bufK, bufK, bufK);
    ln_kernel<<<dim3(16, 4, 32), gb, 0, stream>>>(bufV, 0, bufK, 0, g2, b2, d_out, 1);
}